// Round 12
// baseline (257.347 us; speedup 1.0000x reference)
//
#include <hip/hip_runtime.h>
#include <hip/hip_bf16.h>

typedef float f4 __attribute__((ext_vector_type(4)));
typedef short bf16x8 __attribute__((ext_vector_type(8)));

#define D 2048
#define RANK 16
#define NT 1024        // 16 waves
#define ROWS 32        // rows per block

__device__ __forceinline__ short bf16_of(float x) {
    return __builtin_bit_cast(short, __float2bfloat16(x));
}

__device__ __forceinline__ bf16x8 cvt8(f4 lo, f4 hi) {
    bf16x8 r;
    r[0] = bf16_of(lo.x); r[1] = bf16_of(lo.y);
    r[2] = bf16_of(lo.z); r[3] = bf16_of(lo.w);
    r[4] = bf16_of(hi.x); r[5] = bf16_of(hi.y);
    r[6] = bf16_of(hi.z); r[7] = bf16_of(hi.w);
    return r;
}

__device__ __forceinline__ float bf2f(short s) {
    return __uint_as_float(((unsigned)(unsigned short)s) << 16);
}

// LDS-drain-only barrier: global loads/stores stay in flight across it.
__device__ __forceinline__ void barrier_lgkm() {
    asm volatile("s_waitcnt lgkmcnt(0)" ::: "memory");
    __builtin_amdgcn_s_barrier();
}

// out = h @ (A@B)^T via rank-16. Dense-packed fused kernel:
//   1024 thr = 16 waves = 2 row-groups x 8 K-slices; 32 rows/block;
//   grid = 512 = EXACTLY 2 blocks/CU, all co-resident from t=0
//   (launch_bounds(1024,8) caps VGPR at 64 = 8 waves/SIMD; LDS 18KB x2).
// One generation, no ramps, 32 waves/CU of short independent streams --
// vs R5's ~12. Body is the proven R5/R7 one: MFMA phase1 (verified map),
// fp32 LDS merge, A-as-bf16-regs phase2, coalesced NT f4 stores, and only
// two lgkm-only barriers per block lifetime.
__global__ __launch_bounds__(NT, 8)
void lora_dense(const float* __restrict__ h, const float* __restrict__ A,
                const float* __restrict__ B, float* __restrict__ out) {
    const int tid  = threadIdx.x;
    const int w    = tid >> 6;
    const int rg   = w >> 3;           // row-group 0/1
    const int ks   = w & 7;            // K-slice
    const int lane = tid & 63;
    const int m16  = lane & 15;
    const int kg   = lane >> 4;
    const long brow = (long)blockIdx.x * ROWS;

    __shared__ f4 ldsT[2][8][16][4];   // [rg][ks][row][rank-quad]
    __shared__ f4 tt[ROWS][4];         // merged t, fp32

    // ---- A slice as bf16 (16 VGPR): e = (tid&511)*4 + j ----
    const int e0 = (tid & 511) * 4;
    bf16x8 Abf[4][2];
#pragma unroll
    for (int j = 0; j < 4; ++j) {
        const float* pa = A + (long)(e0 + j) * RANK;
        Abf[j][0] = cvt8(*(const f4*)(pa), *(const f4*)(pa + 4));
        Abf[j][1] = cvt8(*(const f4*)(pa + 8), *(const f4*)(pa + 12));
    }

    // ---- phase 1: wave (rg,ks) -> rows rg*16..+15, K in [ks*256,+256) ----
    const float* pB = B + (long)m16 * D + ks * 256 + kg * 8;
    const float* ph = h + (brow + rg * 16 + m16) * D + ks * 256 + kg * 8;

    f4 a0 = {0.f, 0.f, 0.f, 0.f}, a1 = {0.f, 0.f, 0.f, 0.f};
#pragma unroll
    for (int s = 0; s < 4; ++s) {
        f4 bl = *(const f4*)(pB + s * 32);
        f4 bh = *(const f4*)(pB + s * 32 + 4);
        f4 hl = *(const f4*)(ph + s * 32);
        f4 hh = *(const f4*)(ph + s * 32 + 4);
        a0 = __builtin_amdgcn_mfma_f32_16x16x32_bf16(
            cvt8(bl, bh), cvt8(hl, hh), a0, 0, 0, 0);
    }
#pragma unroll
    for (int s = 4; s < 8; ++s) {
        f4 bl = *(const f4*)(pB + s * 32);
        f4 bh = *(const f4*)(pB + s * 32 + 4);
        f4 hl = *(const f4*)(ph + s * 32);
        f4 hh = *(const f4*)(ph + s * 32 + 4);
        a1 = __builtin_amdgcn_mfma_f32_16x16x32_bf16(
            cvt8(bl, bh), cvt8(hl, hh), a1, 0, 0, 0);
    }
    ldsT[rg][ks][m16][kg] = a0 + a1;

    barrier_lgkm();                    // ldsT ready
    if (tid < 128) {
        const int mrg = tid >> 6, r = (tid >> 2) & 15, q = tid & 3;
        f4 s = ldsT[mrg][0][r][q];
#pragma unroll
        for (int k = 1; k < 8; ++k) s += ldsT[mrg][k][r][q];
        tt[mrg * 16 + r][q] = s;
    }
    barrier_lgkm();                    // tt ready

    // ---- phase 2: 16 iters x 2 rows; thread covers e0..e0+3 ----
    const int rbase = tid >> 9;        // 0/1: which row within the pair
    float* po = out + (brow + rbase) * D + e0;
#pragma unroll 4
    for (int i = 0; i < 16; ++i) {
        const int r = i * 2 + rbase;
        const f4 t0 = tt[r][0], t1 = tt[r][1];
        const f4 t2 = tt[r][2], t3 = tt[r][3];
        f4 res;
#pragma unroll
        for (int j = 0; j < 4; ++j) {
            const bf16x8 lo = Abf[j][0], hi = Abf[j][1];
            float v;
            v  = t0.x * bf2f(lo[0]) + t0.y * bf2f(lo[1]) +
                 t0.z * bf2f(lo[2]) + t0.w * bf2f(lo[3]);
            v += t1.x * bf2f(lo[4]) + t1.y * bf2f(lo[5]) +
                 t1.z * bf2f(lo[6]) + t1.w * bf2f(lo[7]);
            v += t2.x * bf2f(hi[0]) + t2.y * bf2f(hi[1]) +
                 t2.z * bf2f(hi[2]) + t2.w * bf2f(hi[3]);
            v += t3.x * bf2f(hi[4]) + t3.y * bf2f(hi[5]) +
                 t3.z * bf2f(hi[6]) + t3.w * bf2f(hi[7]);
            res[j] = v;
        }
        __builtin_nontemporal_store(res, (f4*)(po + (long)i * 2 * D));
    }
}

extern "C" void kernel_launch(void* const* d_in, const int* in_sizes, int n_in,
                              void* d_out, int out_size, void* d_ws,
                              size_t ws_size, hipStream_t stream) {
    const float* h = (const float*)d_in[0];
    const float* A = (const float*)d_in[1];
    const float* B = (const float*)d_in[2];
    float* out = (float*)d_out;

    const int n_rows = in_sizes[0] / D;   // 16384
    const int blocks = n_rows / ROWS;     // 512

    hipLaunchKernelGGL(lora_dense, dim3(blocks), dim3(NT), 0, stream,
                       h, A, B, out);
}

// Round 13
// 72.588 us; speedup vs baseline: 3.5453x; 3.5453x over previous
//
#include <hip/hip_runtime.h>
#include <hip/hip_bf16.h>

typedef float f4 __attribute__((ext_vector_type(4)));
typedef short bf16x8 __attribute__((ext_vector_type(8)));

#define D 2048
#define RANK 16
#define TILE 16      // rows per block (one MFMA row-tile)
#define NT 512       // 8 waves

__device__ __forceinline__ short bf16_of(float x) {
    return __builtin_bit_cast(short, __float2bfloat16(x));
}

__device__ __forceinline__ bf16x8 cvt8(f4 lo, f4 hi) {
    bf16x8 r;
    r[0] = bf16_of(lo.x); r[1] = bf16_of(lo.y);
    r[2] = bf16_of(lo.z); r[3] = bf16_of(lo.w);
    r[4] = bf16_of(hi.x); r[5] = bf16_of(hi.y);
    r[6] = bf16_of(hi.z); r[7] = bf16_of(hi.w);
    return r;
}

__device__ __forceinline__ float dot4(f4 a, f4 b) {
    return a.x * b.x + a.y * b.y + a.z * b.z + a.w * b.w;
}

// Round-5 kernel (best measured: 61.8 us, ideal traffic) with EXACTLY ONE
// change: plain stores instead of __builtin_nontemporal_store.
// Theory: NT forced all 131 MB of out to HBM inside the dispatch at the
// measured ~3.5 TB/s write rate (~37 us serial write phase). Plain stores
// let L2/L3 absorb the output (h+out = 256 MB = L3 size) and drain the
// dirty lines lazily -- overlapped with the next replay's read phase --
// at the cost of h's L3 residency (FETCH 67 -> ~131 MB).
__global__ __launch_bounds__(NT, 4)
void lora_v13(const float* __restrict__ h, const float* __restrict__ A,
              const float* __restrict__ B, float* __restrict__ out) {
    const int tid  = threadIdx.x;
    const int wave = tid >> 6;
    const int lane = tid & 63;
    const int m16  = lane & 15;
    const int kg   = lane >> 4;
    const long row0 = (long)blockIdx.x * TILE;

    __shared__ f4 ldsT[8][16][4];   // per-wave T partials
    __shared__ f4 tt[16][4];        // merged t[row][rank-quad], fp32

    // ---- prefetch A slice for phase2 (in flight during phase1) ----------
    f4 Ae[4][4];
#pragma unroll
    for (int j = 0; j < 4; ++j)
#pragma unroll
        for (int q = 0; q < 4; ++q)
            Ae[j][q] = *(const f4*)(A + (long)(tid * 4 + j) * RANK + q * 4);

    // ---- phase 1: per-wave MFMA over d-slice [wave*256, wave*256+256) ----
    const float* pB = B + (long)m16 * D + wave * 256 + kg * 8;
    const float* ph = h + (row0 + m16) * D + wave * 256 + kg * 8;

    f4 acc = {0.f, 0.f, 0.f, 0.f};
#pragma unroll
    for (int s = 0; s < 8; ++s) {
        f4 a0 = *(const f4*)(pB + s * 32);
        f4 a1 = *(const f4*)(pB + s * 32 + 4);
        f4 b0 = *(const f4*)(ph + s * 32);
        f4 b1 = *(const f4*)(ph + s * 32 + 4);
        acc = __builtin_amdgcn_mfma_f32_16x16x32_bf16(
            cvt8(a0, a1), cvt8(b0, b1), acc, 0, 0, 0);
    }
    ldsT[wave][m16][kg] = acc;
    __syncthreads();

    // ---- merge 8 wave-partials (fp32) --------------------------------
    if (tid < 64) {
        const int r = tid >> 2, q = tid & 3;
        f4 s = ldsT[0][r][q];
#pragma unroll
        for (int w = 1; w < 8; ++w) s += ldsT[w][r][q];
        tt[r][q] = s;
    }
    __syncthreads();

    // ---- phase 2: out[row][e0..e0+3] for 16 rows, coalesced stores ----
    float* po = out + row0 * D + tid * 4;
#pragma unroll
    for (int r = 0; r < TILE; ++r) {
        const f4 t0 = tt[r][0], t1 = tt[r][1], t2 = tt[r][2], t3 = tt[r][3];
        f4 res;
        res.x = dot4(t0, Ae[0][0]) + dot4(t1, Ae[0][1]) +
                dot4(t2, Ae[0][2]) + dot4(t3, Ae[0][3]);
        res.y = dot4(t0, Ae[1][0]) + dot4(t1, Ae[1][1]) +
                dot4(t2, Ae[1][2]) + dot4(t3, Ae[1][3]);
        res.z = dot4(t0, Ae[2][0]) + dot4(t1, Ae[2][1]) +
                dot4(t2, Ae[2][2]) + dot4(t3, Ae[2][3]);
        res.w = dot4(t0, Ae[3][0]) + dot4(t1, Ae[3][1]) +
                dot4(t2, Ae[3][2]) + dot4(t3, Ae[3][3]);
        *(f4*)(po + (long)r * D) = res;     // plain store: L2/L3-absorbed
    }
}

extern "C" void kernel_launch(void* const* d_in, const int* in_sizes, int n_in,
                              void* d_out, int out_size, void* d_ws,
                              size_t ws_size, hipStream_t stream) {
    const float* h = (const float*)d_in[0];
    const float* A = (const float*)d_in[1];
    const float* B = (const float*)d_in[2];
    float* out = (float*)d_out;

    const int n_rows = in_sizes[0] / D;   // 16384
    const int blocks = n_rows / TILE;     // 1024

    hipLaunchKernelGGL(lora_v13, dim3(blocks), dim3(NT), 0, stream,
                       h, A, B, out);
}